// Round 5
// baseline (120.231 us; speedup 1.0000x reference)
//
#include <hip/hip_runtime.h>
#include <hip/hip_fp16.h>
#include <math.h>

// Problem constants
constexpr int BS  = 8;
constexpr int NS  = 2048;
constexpr int NCP = 8;
constexpr int NH  = 8;
constexpr int C   = 128;
constexpr int HID = 128;
constexpr int RR  = 128;

constexpr int QPB = 8;    // queries per block (attn)
constexpr int VEC = 4;    // channels per thread (attn)

constexpr int NPOS = RR * RR;                       // 16384 positions per slab
constexpr size_t PLE = (size_t)BS * NPOS * C;       // elems per plane-type slab

// transpose geometry: 64 positions x all 128 channels per block
constexpr int TPOS   = 64;
constexpr int NBLK_T = 3 * BS * (NPOS / TPOS);      // 6144

// channel<->slot permutation: slot s holds channel (s>>3) + 16*(s&7)
__host__ __device__ __forceinline__ int ch_of_slot(int s) {
    return (s >> 3) + ((s & 7) << 4);
}
__host__ __device__ __forceinline__ int slot_of_ch(int c) {
    return ((c & 15) << 3) | (c >> 4);
}

typedef __attribute__((address_space(3))) float lds_f;
typedef const __attribute__((address_space(1))) float glb_f;

// ---------------------------------------------------------------------------
struct F4 { float x, y, z, w; };
__device__ __forceinline__ F4 f4add(F4 a, F4 b) {
    return F4{a.x + b.x, a.y + b.y, a.z + b.z, a.w + b.w};
}
__device__ __forceinline__ F4 f4fma(F4 acc, float s, F4 v) {
    return F4{fmaf(s, v.x, acc.x), fmaf(s, v.y, acc.y),
              fmaf(s, v.z, acc.z), fmaf(s, v.w, acc.w)};
}
__device__ __forceinline__ F4 cvt4(int2 r) {
    __half2 h0 = *reinterpret_cast<__half2*>(&r.x);
    __half2 h1 = *reinterpret_cast<__half2*>(&r.y);
    float2 f0 = __half22float2(h0);
    float2 f1 = __half22float2(h1);
    return F4{f0.x, f0.y, f1.x, f1.y};
}

// ---------------------------------------------------------------------------
// Fused transpose (fp32 [C][R][R] -> fp16 [R*R][slot]) + weight prep.
// Transpose uses async global_load_lds with XOR-swizzled global source.
// Blocks [0, 6144): transpose tiles. Blocks [6144, 6274): weight prep.
// ---------------------------------------------------------------------------
__global__ __launch_bounds__(256) void trans_prep_k(
    const float* __restrict__ pxz, const float* __restrict__ pxy,
    const float* __restrict__ pyz, __half* __restrict__ dst,
    const float* __restrict__ Wv, const float* __restrict__ bv,
    const float* __restrict__ Ww, const float* __restrict__ bw,
    const float* __restrict__ Wo,
    float* __restrict__ Wf, float* __restrict__ bf,
    float* __restrict__ Ww2, float* __restrict__ bw2)
{
    const int bid = blockIdx.x;
    const int t   = threadIdx.x;

    if (bid >= NBLK_T) {
        // ----- weight prep (channel-permuted rows) -----
        const int k = bid - NBLK_T;
        const int c = t;
        if (c >= 128) return;
        if (k < 128) {
            // Wf[slot k][c] = sum_j Wv[ch(k)][j] * Wo[j][c]
            const int kk = ch_of_slot(k);
            float acc = 0.f;
            #pragma unroll 8
            for (int j = 0; j < 128; ++j) acc += Wv[kk * 128 + j] * Wo[j * 128 + c];
            Wf[k * 128 + c] = acc;
        } else if (k == 128) {
            float acc = 0.f;
            #pragma unroll 8
            for (int j = 0; j < 128; ++j) acc += bv[j] * Wo[j * 128 + c];
            bf[c] = acc;
        } else {  // k == 129: Ww2[slot c][h] = sum_i Ww[ch(c)][i*8+h]
            const int cc = ch_of_slot(c);
            float s[NH];
            #pragma unroll
            for (int h = 0; h < NH; ++h) s[h] = 0.f;
            #pragma unroll
            for (int i = 0; i < NCP; ++i)
                #pragma unroll
                for (int h = 0; h < NH; ++h) s[h] += Ww[cc * (NCP * NH) + i * NH + h];
            #pragma unroll
            for (int h = 0; h < NH; ++h) Ww2[c * NH + h] = s[h];
            if (c < NH) {
                float tt = 0.f;
                #pragma unroll
                for (int i = 0; i < NCP; ++i) tt += bw[i * NH + c];
                bw2[c] = tt;
            }
        }
        return;
    }

    // ----- transpose tile: 128 channels x 64 positions -----
    // XCD-align: batch = bid & 7 so batch b's planes are produced on XCD b.
    const int b    = bid & 7;
    const int idx  = bid >> 3;            // 0..767
    const int pl   = idx >> 8;            // 0..2
    const int tile = idx & 255;           // 0..255
    const int n0   = tile * TPOS;

    const float* src = (pl == 0 ? pxz : (pl == 1 ? pxy : pyz))
                       + (size_t)b * C * NPOS;
    __half* d = dst + (size_t)(pl * BS + b) * ((size_t)NPOS * C);

    // LDS: [c][64 pos] fp32, linear (32 KB). Source blocks XOR-swizzled.
    __shared__ float lds[C * TPOS];

    const int wave = t >> 6;
    const int lane = t & 63;
    const int cw   = lane >> 4;           // channel within 4-channel group
    const int blk  = lane & 15;           // dest 16B block within channel row

    // Phase A: async stage. 8 instrs/wave, each 64 lanes x 16B = 4 ch x 256B.
    #pragma unroll
    for (int j = 0; j < 8; ++j) {
        const int c0 = wave * 32 + j * 4;
        const int c  = c0 + cw;
        const int sb = blk ^ (c & 15);    // swizzled source block
        glb_f* gp = (glb_f*)(src + (size_t)c * NPOS + n0 + sb * 4);
        lds_f* lp = (lds_f*)(&lds[c0 * TPOS]);
        __builtin_amdgcn_global_load_lds(gp, lp, 16, 0, 0);
    }
    __syncthreads();   // compiler drains vmcnt before barrier

    // Phase B: transposed read (2-way conflict via swizzle) + fp16 pack + store.
    // Lane handles (position n, lane-group g): channels g, g+16, ..., g+112
    // packed into slots g*8 .. g*8+7 -> one 16B coalesced store.
    #pragma unroll
    for (int i = 0; i < 4; ++i) {
        const int li = i * 256 + t;
        const int n  = li >> 4;           // 0..63
        const int g  = li & 15;
        const int ro = (((n >> 2) ^ g) << 2) + (n & 3);  // swizzled row offset
        unsigned u[4];
        #pragma unroll
        for (int jj = 0; jj < 4; ++jj) {
            const float vA = lds[(g + 32 * jj) * TPOS + ro];
            const float vB = lds[(g + 32 * jj + 16) * TPOS + ro];
            __half2 h = __floats2half2_rn(vA, vB);
            u[jj] = *reinterpret_cast<unsigned*>(&h);
        }
        *reinterpret_cast<uint4*>(d + (size_t)(n0 + n) * C + g * 8) =
            make_uint4(u[0], u[1], u[2], u[3]);
    }
}

// ---------------------------------------------------------------------------
// Bilinear sample of 4 fp16 slots; base already offset by batch + slot4.
// ---------------------------------------------------------------------------
__device__ __forceinline__ F4 samp(const __half* __restrict__ base, float u, float v)
{
    float x = fminf(fmaxf(u, 0.f), 1.f) * (float)(RR - 1);
    float y = fminf(fmaxf(v, 0.f), 1.f) * (float)(RR - 1);
    float x0f = floorf(x), y0f = floorf(y);
    float wx = x - x0f, wy = y - y0f;
    int x0 = (int)x0f, y0 = (int)y0f;
    int x1 = min(x0 + 1, RR - 1), y1 = min(y0 + 1, RR - 1);
    int r0 = y0 << 14, r1 = y1 << 14, cc0 = x0 << 7, cc1 = x1 << 7;
    int2 a00 = *reinterpret_cast<const int2*>(base + r0 + cc0);
    int2 a01 = *reinterpret_cast<const int2*>(base + r0 + cc1);
    int2 a10 = *reinterpret_cast<const int2*>(base + r1 + cc0);
    int2 a11 = *reinterpret_cast<const int2*>(base + r1 + cc1);
    float w00 = (1.f - wx) * (1.f - wy), w01 = wx * (1.f - wy);
    float w10 = (1.f - wx) * wy,         w11 = wx * wy;
    F4 f00 = cvt4(a00), f01 = cvt4(a01), f10 = cvt4(a10), f11 = cvt4(a11);
    F4 r;
    r.x = f00.x * w00 + f01.x * w01 + f10.x * w10 + f11.x * w11;
    r.y = f00.y * w00 + f01.y * w01 + f10.y * w10 + f11.y * w11;
    r.z = f00.z * w00 + f01.z * w01 + f10.z * w10 + f11.z * w11;
    r.w = f00.w * w00 + f01.w * w01 + f10.w * w10 + f11.w * w11;
    return r;
}

// ---------------------------------------------------------------------------
// Main fused kernel: 256 threads = 8 queries x 32 threads (4 slots each).
// Planes/weights are in slot (permuted-channel) order; output in original.
// ---------------------------------------------------------------------------
__global__ __launch_bounds__(256) void attn_k(
    const float* __restrict__ qpos,
    const __half* __restrict__ planes,   // [3][B][R][R][slot] fp16
    const float* __restrict__ cpts,
    const float* __restrict__ Ww2, const float* __restrict__ bw2,
    const float* __restrict__ Wf,  const float* __restrict__ bf,
    const float* __restrict__ bo,
    float* __restrict__ out)
{
    // XCD-aware swizzle (gridDim.x = 2048, divisible by 8)
    const int nb   = gridDim.x;
    const int cpx  = nb >> 3;
    const int sbid = (blockIdx.x & 7) * cpx + (blockIdx.x >> 3);

    const int tid  = threadIdx.x;
    const int ql   = tid >> 5;
    const int lane = tid & 31;
    const int c4   = lane * VEC;       // slot index
    const int q    = sbid * QPB + ql;
    const int b    = q >> 11;          // q / NS

    const float* qp = qpos + (size_t)q * 9;
    const float px = qp[0], py = qp[1], pz = qp[2];
    const float a1x = qp[3], a1y = qp[4], a1z = qp[5];
    const float a2x = qp[6], a2y = qp[7], a2z = qp[8];

    float inv = 1.f / sqrtf(a1x * a1x + a1y * a1y + a1z * a1z);
    float b1x = a1x * inv, b1y = a1y * inv, b1z = a1z * inv;
    float dd  = b1x * a2x + b1y * a2y + b1z * a2z;
    float b2x = a2x - dd * b1x, b2y = a2y - dd * b1y, b2z = a2z - dd * b1z;
    inv = 1.f / sqrtf(b2x * b2x + b2y * b2y + b2z * b2z);
    b2x *= inv; b2y *= inv; b2z *= inv;
    float b3x = b1y * b2z - b1z * b2y;
    float b3y = b1z * b2x - b1x * b2z;
    float b3z = b1x * b2y - b1y * b2x;

    const __half* Pxz = planes + (size_t)b * ((size_t)NPOS * C) + c4;
    const __half* Pxy = Pxz + PLE;
    const __half* Pyz = Pxy + PLE;

    // ---- pass 1: base feature (4 slots) ----
    F4 feat = f4add(f4add(samp(Pxz, px, pz), samp(Pxy, px, py)), samp(Pyz, py, pz));

    // ---- ws[h] = feat . Ww2[:,h] + bw2[h] (Ww2 already slot-permuted) ----
    float p[NH];
    #pragma unroll
    for (int h = 0; h < NH; ++h) p[h] = 0.f;
    {
        const float* wr = Ww2 + c4 * NH;
        const float fv[VEC] = {feat.x, feat.y, feat.z, feat.w};
        #pragma unroll
        for (int i = 0; i < VEC; ++i)
            #pragma unroll
            for (int h = 0; h < NH; ++h) p[h] += fv[i] * wr[i * NH + h];
    }
    #pragma unroll
    for (int off = 16; off >= 1; off >>= 1)
        #pragma unroll
        for (int h = 0; h < NH; ++h) p[h] += __shfl_xor(p[h], off);

    float ws[NH], Ssum = 0.f;
    #pragma unroll
    for (int h = 0; h < NH; ++h) { ws[h] = p[h] + bw2[h]; Ssum += ws[h]; }

    // ---- pass 2: anchors, accumulate comb = sum_g ws[g]*sf[g] ----
    F4 comb = {0.f, 0.f, 0.f, 0.f};
    #pragma unroll 2
    for (int g = 0; g < NCP; ++g) {
        float cx = cpts[g * 3 + 0], cy = cpts[g * 3 + 1], cz = cpts[g * 3 + 2];
        float ax = px + b1x * cx + b1y * cy + b1z * cz;
        float ay = py + b2x * cx + b2y * cy + b2z * cz;
        float az = pz + b3x * cx + b3y * cy + b3z * cz;
        F4 s = f4add(f4add(samp(Pxz, ax, az), samp(Pxy, ax, ay)), samp(Pyz, ay, az));
        comb = f4fma(comb, ws[g], s);
    }

    // ---- stash per-query vectors (slot order) ----
    __shared__ float sComb[QPB][C];
    __shared__ float sFeat[QPB][C];
    __shared__ float sSum[QPB];
    *reinterpret_cast<float4*>(&sComb[ql][c4]) = make_float4(comb.x, comb.y, comb.z, comb.w);
    *reinterpret_cast<float4*>(&sFeat[ql][c4]) = make_float4(feat.x, feat.y, feat.z, feat.w);
    if (lane == 0) sSum[ql] = Ssum;
    __syncthreads();

    // ---- epilogue GEMV: out[c] = comb_slot . Wf[:,c] + Ssum*bf[c] + bo[c] + feat[c]
    const int c  = tid & 127;         // original output channel
    const int sl = slot_of_ch(c);     // where feat[c] lives in slot order
    const int q0 = (tid >> 7) * 4;    // queries q0..q0+3
    float acc[4];
    const float bfc = bf[c], boc = bo[c];
    #pragma unroll
    for (int j = 0; j < 4; ++j)
        acc[j] = sSum[q0 + j] * bfc + boc + sFeat[q0 + j][sl];
    #pragma unroll 4
    for (int k = 0; k < C; ++k) {
        float wf = Wf[k * C + c];
        #pragma unroll
        for (int j = 0; j < 4; ++j) acc[j] += sComb[q0 + j][k] * wf;
    }
    #pragma unroll
    for (int j = 0; j < 4; ++j)
        out[(size_t)(sbid * QPB + q0 + j) * C + c] = acc[j];
}

// ---------------------------------------------------------------------------
extern "C" void kernel_launch(void* const* d_in, const int* in_sizes, int n_in,
                              void* d_out, int out_size, void* d_ws, size_t ws_size,
                              hipStream_t stream)
{
    const float* qpos = (const float*)d_in[0];
    const float* pxz  = (const float*)d_in[1];
    const float* pxy  = (const float*)d_in[2];
    const float* pyz  = (const float*)d_in[3];
    const float* cpts = (const float*)d_in[4];
    const float* Wv   = (const float*)d_in[5];
    const float* bv   = (const float*)d_in[6];
    const float* Ww   = (const float*)d_in[7];
    const float* bw   = (const float*)d_in[8];
    const float* Wo   = (const float*)d_in[9];
    const float* bo   = (const float*)d_in[10];
    float* out = (float*)d_out;

    __half* plh = (__half*)d_ws;
    float*  wsf = (float*)((char*)d_ws + 3 * PLE * sizeof(__half));  // ~96 MB in
    float* Wf  = wsf;                 // 128*128
    float* bf  = Wf + C * HID;        // 128
    float* Ww2 = bf + C;              // 128*8
    float* bw2 = Ww2 + C * NH;        // 8

    // fused transpose + weight prep
    hipLaunchKernelGGL(trans_prep_k, dim3(NBLK_T + 130), dim3(256), 0, stream,
                       pxz, pxy, pyz, plh, Wv, bv, Ww, bw, Wo, Wf, bf, Ww2, bw2);

    // fused main kernel
    hipLaunchKernelGGL(attn_k, dim3(BS * NS / QPB), dim3(256), 0, stream,
                       qpos, plh, cpts, Ww2, bw2, Wf, bf, bo, out);
}